// Round 1
// baseline (262.124 us; speedup 1.0000x reference)
//
#include <hip/hip_runtime.h>
#include <math.h>

#define N_FFT   512
#define HOP     128
#define NBINS   257
#define NSLOTS  1024
#define TWO_PI_F     6.2831853071795864769f
#define INV_TWO_PI_F 0.15915494309189533577f

__device__ __forceinline__ float anti_wrap(float x) {
    return fabsf(x - rintf(x * INV_TWO_PI_F) * TWO_PI_F);
}

// Compute STFT phases of frame t for both signals (packed complex FFT).
// buf: 512 float2 LDS scratch; pr/pg: 257-float LDS outputs.
__device__ void frame_phases(const float* __restrict__ y,
                             const float* __restrict__ g,
                             int t, int T,
                             float2* buf, float* pr, float* pg) {
    const int tid = threadIdx.x;
    // Load frame with reflect padding, bit-reversed positions, pack z = y + i*g
    for (int n = tid; n < N_FFT; n += 256) {
        int j = t * HOP + n - (N_FFT / 2);
        if (j < 0) j = -j;
        else if (j >= T) j = 2 * T - 2 - j;
        unsigned r = __brev((unsigned)n) >> 23;  // 9-bit reversal
        buf[r] = make_float2(y[j], g[j]);
    }
    __syncthreads();
    // 9 radix-2 DIT stages, in-place, 256 butterflies/stage (1 per thread)
    for (int s = 1; s <= 9; s++) {
        const int half = 1 << (s - 1);
        const int j = tid & (half - 1);
        const int i1 = ((tid >> (s - 1)) << s) + j;
        const int i2 = i1 + half;
        float ang = -(float)M_PI * (float)j / (float)half;
        float sn, cs;
        __sincosf(ang, &sn, &cs);
        float2 a = buf[i1], b = buf[i2];
        float2 tt = make_float2(cs * b.x - sn * b.y, cs * b.y + sn * b.x);
        buf[i1] = make_float2(a.x + tt.x, a.y + tt.y);
        buf[i2] = make_float2(a.x - tt.x, a.y - tt.y);
        __syncthreads();
    }
    // Unpack Hermitian halves, phases via atan2 (scale 0.5 irrelevant to angle)
    for (int k = tid; k < NBINS; k += 256) {
        float2 zk = buf[k];
        float2 zn = buf[(N_FFT - k) & (N_FFT - 1)];
        float yr = zk.x + zn.x, yi = zk.y - zn.y;   // Y[k] = (Z[k]+conj(Z[N-k]))/2
        float gr = zk.y + zn.y, gi = zn.x - zk.x;   // G[k] = -i(Z[k]-conj(Z[N-k]))/2
        pr[k] = atan2f(yi, yr);
        pg[k] = atan2f(gi, gr);
    }
    __syncthreads();
}

__global__ __launch_bounds__(256) void phase_loss_kernel(
        const float* __restrict__ y, const float* __restrict__ g,
        float* __restrict__ acc, int T) {
    __shared__ float2 buf[N_FFT];
    __shared__ float prc[NBINS], pgc[NBINS], prp[NBINS], pgp[NBINS];
    __shared__ float wsum[3][4];
    const int t = blockIdx.x;
    const int tid = threadIdx.x;

    frame_phases(y, g, t, T, buf, prc, pgc);
    const bool have_prev = (t > 0);
    if (have_prev) frame_phases(y, g, t - 1, T, buf, prp, pgp);

    float ip = 0.f, gd = 0.f, iaf = 0.f;
    for (int f = tid; f < NBINS; f += 256) {
        float d = prc[f] - pgc[f];
        float awd = anti_wrap(d);
        ip += awd;
        // gd row 0: aw(-pr[0]+pg[0]) == awd
        gd += (f == 0) ? awd
                       : anti_wrap((prc[f - 1] - prc[f]) - (pgc[f - 1] - pgc[f]));
        // iaf col 0: aw(-pr+pg) == awd
        iaf += have_prev ? anti_wrap((prp[f] - prc[f]) - (pgp[f] - pgc[f]))
                         : awd;
    }
    // wave-64 shuffle reduce, then cross-wave via LDS
    for (int off = 32; off; off >>= 1) {
        ip  += __shfl_down(ip, off);
        gd  += __shfl_down(gd, off);
        iaf += __shfl_down(iaf, off);
    }
    const int lane = tid & 63, wv = tid >> 6;
    if (lane == 0) { wsum[0][wv] = ip; wsum[1][wv] = gd; wsum[2][wv] = iaf; }
    __syncthreads();
    if (tid == 0) {
        float s0 = wsum[0][0] + wsum[0][1] + wsum[0][2] + wsum[0][3];
        float s1 = wsum[1][0] + wsum[1][1] + wsum[1][2] + wsum[1][3];
        float s2 = wsum[2][0] + wsum[2][1] + wsum[2][2] + wsum[2][3];
        const int slot = (int)(blockIdx.x & (NSLOTS - 1));
        atomicAdd(acc + 0 * NSLOTS + slot, s0);
        atomicAdd(acc + 1 * NSLOTS + slot, s1);
        atomicAdd(acc + 2 * NSLOTS + slot, s2);
    }
}

__global__ __launch_bounds__(256) void finalize_kernel(
        const float* __restrict__ acc, float* __restrict__ out, float inv_count) {
    const int tid = threadIdx.x;
    __shared__ float wsum[4];
    for (int l = 0; l < 3; l++) {
        float v = acc[l * NSLOTS + tid]       + acc[l * NSLOTS + tid + 256]
                + acc[l * NSLOTS + tid + 512] + acc[l * NSLOTS + tid + 768];
        for (int off = 32; off; off >>= 1) v += __shfl_down(v, off);
        if ((tid & 63) == 0) wsum[tid >> 6] = v;
        __syncthreads();
        if (tid == 0) out[l] = (wsum[0] + wsum[1] + wsum[2] + wsum[3]) * inv_count;
        __syncthreads();
    }
}

extern "C" void kernel_launch(void* const* d_in, const int* in_sizes, int n_in,
                              void* d_out, int out_size, void* d_ws, size_t ws_size,
                              hipStream_t stream) {
    const float* y = (const float*)d_in[0];
    const float* g = (const float*)d_in[1];
    float* out = (float*)d_out;
    float* acc = (float*)d_ws;
    const int T = in_sizes[0];
    const int n_frames = T / HOP + 1;  // center-padded: (T+512-512)/128 + 1

    hipMemsetAsync(d_ws, 0, 3 * NSLOTS * sizeof(float), stream);
    phase_loss_kernel<<<n_frames, 256, 0, stream>>>(y, g, acc, T);
    const float inv_count = 1.0f / ((float)NBINS * (float)n_frames);
    finalize_kernel<<<1, 256, 0, stream>>>(acc, out, inv_count);
}

// Round 2
// 216.007 us; speedup vs baseline: 1.2135x; 1.2135x over previous
//
#include <hip/hip_runtime.h>
#include <math.h>

#define N_FFT   512
#define HOP     128
#define NBINS   257
#define NSLOTS  256
#define FPB     8      // frames per block
#define PI_F    3.14159265358979323846f
#define PI2_F   1.57079632679489661923f

#define PAD(i) ((i) + ((i) >> 5))

// |atan2(im, re)| in [0, pi]. Max err ~1e-5 rad — negligible in an 8.4M mean.
__device__ __forceinline__ float abs_angle(float re, float im) {
    float a = fabsf(im), b = fabsf(re);
    float mn = fminf(a, b), mx = fmaxf(a, b);
    float t = __fdividef(mn, fmaxf(mx, 1e-37f));
    float t2 = t * t;
    float p = fmaf(t2, -0.0117212f, 0.05265332f);
    p = fmaf(t2, p, -0.11643287f);
    p = fmaf(t2, p, 0.19354346f);
    p = fmaf(t2, p, -0.33262347f);
    p = fmaf(t2, p, 0.99997726f);
    float r = t * p;
    r = (a > b) ? (PI2_F - r) : r;
    r = (re < 0.f) ? (PI_F - r) : r;
    return r;
}

__global__ __launch_bounds__(256) void phase_loss_kernel(
        const float* __restrict__ y, const float* __restrict__ g,
        float* __restrict__ acc, int* __restrict__ ticket,
        float* __restrict__ out, int T, int n_frames, float inv_count) {
    __shared__ float s_re[528], s_im[528];       // padded: i + i/32
    __shared__ float2 Cbuf[2][NBINS];            // cross-spectra ping-pong
    __shared__ float wsum[3][4];
    __shared__ int is_last;

    const int tid = threadIdx.x;

    // Twiddles depend only on tid -> registers, computed once per block.
    // DIF stage s (half h = 256>>s): W = exp(-i*pi*m/256), m = (tid&(h-1))<<s
    float twr[9], twi[9];
    #pragma unroll
    for (int s = 0; s < 9; s++) {
        int h = 256 >> s;
        int m = (tid & (h - 1)) << s;
        float ang = -PI_F * (float)m * (1.0f / 256.0f);
        __sincosf(ang, &twi[s], &twr[s]);
    }

    const int t0 = blockIdx.x * FPB;
    float ip = 0.f, gd = 0.f, iaf = 0.f;
    int cur = 0;
    bool have_prev = (t0 > 0);

    // load frame t (reflect pad), packed complex FFT (z = y + i*g, DIF),
    // unpack Hermitian halves, store C = Y*conj(G) (scaled) into Cbuf[dst].
    auto do_frame = [&](int t, int dst) {
        #pragma unroll
        for (int hh = 0; hh < 2; hh++) {
            int n = tid + hh * 256;
            int j = t * HOP + n - 256;
            j = (j < 0) ? -j : j;
            j = (j >= T) ? (2 * T - 2 - j) : j;
            s_re[PAD(n)] = y[j];
            s_im[PAD(n)] = g[j];
        }
        __syncthreads();
        #pragma unroll
        for (int s = 0; s < 9; s++) {
            const int h = 256 >> s;
            const int p = 8 - s;
            const int i1 = ((tid >> p) << (p + 1)) + (tid & (h - 1));
            const int i2 = i1 + h;
            float ar = s_re[PAD(i1)], ai = s_im[PAD(i1)];
            float br = s_re[PAD(i2)], bi = s_im[PAD(i2)];
            float sr = ar - br, si = ai - bi;
            s_re[PAD(i1)] = ar + br;
            s_im[PAD(i1)] = ai + bi;
            s_re[PAD(i2)] = fmaf(sr, twr[s], -si * twi[s]);
            s_im[PAD(i2)] = fmaf(sr, twi[s],  si * twr[s]);
            __syncthreads();
        }
        // DIF output is bit-reversed: bin k sits at brev9(k).
        for (int k = tid; k < NBINS; k += 256) {
            int r1 = __brev((unsigned)k) >> 23;
            int r2 = __brev((unsigned)((N_FFT - k) & (N_FFT - 1))) >> 23;
            float zkr = s_re[PAD(r1)], zki = s_im[PAD(r1)];
            float znr = s_re[PAD(r2)], zni = s_im[PAD(r2)];
            float ur = zkr + znr, ui = zki - zni;   // 2*Y
            float vx = zkr - znr, vy = zki + zni;   // 2i*G
            // C = Y*conj(G) (x4 scale, angle-invariant)
            Cbuf[dst][k] = make_float2(fmaf(ur, vy, -ui * vx),
                                       fmaf(ur, vx,  ui * vy));
        }
        __syncthreads();
    };

    if (have_prev) do_frame(t0 - 1, cur ^ 1);

    for (int c = 0; c < FPB; c++) {
        int t = t0 + c;
        if (t >= n_frames) break;
        do_frame(t, cur);
        for (int f = tid; f < NBINS; f += 256) {
            float2 cc = Cbuf[cur][f];
            float aw = abs_angle(cc.x, cc.y);
            ip += aw;
            if (f == 0) {
                gd += aw;
            } else {
                float2 cm = Cbuf[cur][f - 1];
                gd += abs_angle(fmaf(cm.x, cc.x, cm.y * cc.y),
                                fmaf(cm.y, cc.x, -cm.x * cc.y));
            }
            if (have_prev) {
                float2 cp = Cbuf[cur ^ 1][f];
                iaf += abs_angle(fmaf(cp.x, cc.x, cp.y * cc.y),
                                 fmaf(cp.y, cc.x, -cp.x * cc.y));
            } else {
                iaf += aw;
            }
        }
        cur ^= 1;
        have_prev = true;
        __syncthreads();
    }

    // block reduce: wave shuffle then LDS
    for (int off = 32; off; off >>= 1) {
        ip  += __shfl_down(ip, off);
        gd  += __shfl_down(gd, off);
        iaf += __shfl_down(iaf, off);
    }
    const int lane = tid & 63, wv = tid >> 6;
    if (lane == 0) { wsum[0][wv] = ip; wsum[1][wv] = gd; wsum[2][wv] = iaf; }
    __syncthreads();
    if (tid == 0) {
        const int slot = (int)(blockIdx.x & (NSLOTS - 1));
        atomicAdd(acc + 0 * NSLOTS + slot, wsum[0][0] + wsum[0][1] + wsum[0][2] + wsum[0][3]);
        atomicAdd(acc + 1 * NSLOTS + slot, wsum[1][0] + wsum[1][1] + wsum[1][2] + wsum[1][3]);
        atomicAdd(acc + 2 * NSLOTS + slot, wsum[2][0] + wsum[2][1] + wsum[2][2] + wsum[2][3]);
        __threadfence();
        is_last = (atomicAdd(ticket, 1) == (int)gridDim.x - 1);
    }
    __syncthreads();
    // last block reduces the slot grid and writes the 3 outputs
    if (is_last) {
        for (int l = 0; l < 3; l++) {
            float v = __hip_atomic_load(acc + l * NSLOTS + tid,
                                        __ATOMIC_RELAXED, __HIP_MEMORY_SCOPE_AGENT);
            for (int off = 32; off; off >>= 1) v += __shfl_down(v, off);
            if (lane == 0) wsum[l][wv] = v;
        }
        __syncthreads();
        if (tid < 3)
            out[tid] = (wsum[tid][0] + wsum[tid][1] + wsum[tid][2] + wsum[tid][3]) * inv_count;
    }
}

extern "C" void kernel_launch(void* const* d_in, const int* in_sizes, int n_in,
                              void* d_out, int out_size, void* d_ws, size_t ws_size,
                              hipStream_t stream) {
    const float* y = (const float*)d_in[0];
    const float* g = (const float*)d_in[1];
    float* out = (float*)d_out;
    float* acc = (float*)d_ws;                       // 3*NSLOTS floats
    int* ticket = (int*)((char*)d_ws + 3 * NSLOTS * sizeof(float));
    const int T = in_sizes[0];
    const int n_frames = T / HOP + 1;                // 32769
    const int n_blocks = (n_frames + FPB - 1) / FPB; // 4097

    hipMemsetAsync(d_ws, 0, 3 * NSLOTS * sizeof(float) + sizeof(int), stream);
    const float inv_count = 1.0f / ((float)NBINS * (float)n_frames);
    phase_loss_kernel<<<n_blocks, 256, 0, stream>>>(y, g, acc, ticket, out,
                                                    T, n_frames, inv_count);
}

// Round 3
// 138.368 us; speedup vs baseline: 1.8944x; 1.5611x over previous
//
#include <hip/hip_runtime.h>
#include <math.h>

#define HOP     128
#define NSLOTS  256
#define FPW     8      // frames per wave (chain length)
#define PI_F    3.14159265358979323846f
#define PI2_F   1.57079632679489661923f
#define K8      0.70710678118654752440f

struct cpx { float x, y; };
__device__ __forceinline__ cpx cadd(cpx a, cpx b){ return {a.x+b.x, a.y+b.y}; }
__device__ __forceinline__ cpx csub(cpx a, cpx b){ return {a.x-b.x, a.y-b.y}; }
__device__ __forceinline__ cpx cmul(cpx a, cpx b){
    return {fmaf(a.x,b.x,-a.y*b.y), fmaf(a.x,b.y, a.y*b.x)};
}
__device__ __forceinline__ cpx cmulc(cpx a, cpx b){  // a*conj(b)
    return {fmaf(a.x,b.x, a.y*b.y), fmaf(a.y,b.x,-a.x*b.y)};
}

// |atan2(im,re)| in [0,pi] — same poly that passed round 2.
__device__ __forceinline__ float abs_angle(float re, float im) {
    float a = fabsf(im), b = fabsf(re);
    float mn = fminf(a, b), mx = fmaxf(a, b);
    float t = __fdividef(mn, fmaxf(mx, 1e-37f));
    float t2 = t * t;
    float p = fmaf(t2, -0.0117212f, 0.05265332f);
    p = fmaf(t2, p, -0.11643287f);
    p = fmaf(t2, p, 0.19354346f);
    p = fmaf(t2, p, -0.33262347f);
    p = fmaf(t2, p, 0.99997726f);
    float r = t * p;
    r = (a > b) ? (PI2_F - r) : r;
    r = (re < 0.f) ? (PI_F - r) : r;
    return r;
}

// In-register 8-point DFT, natural-order output. X[k] = sum_n v[n] W8^{nk}.
__device__ __forceinline__ void dft8(cpx v[8]) {
    cpx a0=cadd(v[0],v[4]), a1=cadd(v[1],v[5]), a2=cadd(v[2],v[6]), a3=cadd(v[3],v[7]);
    cpx b0=csub(v[0],v[4]), b1=csub(v[1],v[5]), b2=csub(v[2],v[6]), b3=csub(v[3],v[7]);
    b1 = cpx{K8*(b1.x+b1.y), K8*(b1.y-b1.x)};   // * e^{-i pi/4}
    b2 = cpx{b2.y, -b2.x};                      // * -i
    b3 = cpx{K8*(b3.y-b3.x), -K8*(b3.x+b3.y)};  // * e^{-3i pi/4}
    cpx c0=cadd(a0,a2), c2=csub(a0,a2);
    cpx c1=cadd(a1,a3), c3=csub(a1,a3); c3 = cpx{c3.y, -c3.x};
    cpx d0=cadd(b0,b2), d2=csub(b0,b2);
    cpx d1=cadd(b1,b3), d3=csub(b1,b3); d3 = cpx{d3.y, -d3.x};
    v[0]=cadd(c0,c1); v[4]=csub(c0,c1);
    v[2]=cadd(c2,c3); v[6]=csub(c2,c3);
    v[1]=cadd(d0,d1); v[5]=csub(d0,d1);
    v[3]=cadd(d2,d3); v[7]=csub(d2,d3);
}

__global__ __launch_bounds__(256) void phase_loss_kernel(
        const float* __restrict__ y, const float* __restrict__ g,
        float* __restrict__ acc, int* __restrict__ ticket,
        float* __restrict__ out, int T, int n_frames, float inv_count) {
    __shared__ float2 xch_all[4][576];   // per-wave transpose scratch
    __shared__ float wsum[3][4];
    __shared__ int is_last;

    const int tid  = threadIdx.x;
    const int lane = tid & 63;
    const int wid  = tid >> 6;
    float2* xch = xch_all[wid];

    // Per-lane twiddles (registers, once per kernel):
    // tw1[k] = W512^{lane*k}, tw2[k] = W64^{(lane&7)*k}
    cpx tw1[8], tw2[8];
    #pragma unroll
    for (int k = 0; k < 8; ++k) {
        float a1 = -(2.0f * PI_F / 512.0f) * (float)(lane * k);
        __sincosf(a1, &tw1[k].y, &tw1[k].x);
        float a2 = -(2.0f * PI_F / 64.0f) * (float)((lane & 7) * k);
        __sincosf(a2, &tw2[k].y, &tw2[k].x);
    }

    float ip = 0.f, gd = 0.f, iaf = 0.f;
    cpx Cp[5];
    const int chain = blockIdx.x * 4 + wid;
    const int t0 = chain * FPW;
    const bool havep = (t0 > 0);

    auto do_frame = [&](int t, bool accum, bool hp) {
        cpx v[8];
        // load: reg r holds sample n2=r stride 64; reflect-padded
        const int base = t * HOP - 256 + lane;
        #pragma unroll
        for (int r = 0; r < 8; ++r) {
            int j = base + r * 64;
            j = (j < 0) ? -j : j;
            j = (j >= T) ? (2 * T - 2 - j) : j;
            v[r].x = y[j]; v[r].y = g[j];
        }
        // ---- stage 1: DFT8 over n2, twiddle W512^{m k0}, m = lane ----
        dft8(v);
        #pragma unroll
        for (int k = 1; k < 8; ++k) v[k] = cmul(v[k], tw1[k]);
        // ---- transpose 1 (pitch 72: conflict-free both sides) ----
        #pragma unroll
        for (int k = 0; k < 8; ++k)
            xch[k * 72 + lane] = make_float2(v[k].x, v[k].y);
        __builtin_amdgcn_s_waitcnt(0xc07f);   // lgkmcnt(0)
        __builtin_amdgcn_wave_barrier();
        {
            const int ra = (lane >> 3) * 72 + (lane & 7);
            #pragma unroll
            for (int r = 0; r < 8; ++r) {
                float2 tmp = xch[ra + r * 8];
                v[r] = cpx{tmp.x, tmp.y};
            }
        }
        // ---- stage 2: DFT8 over n1, twiddle W64^{n0 q0}, n0 = lane&7 ----
        dft8(v);
        #pragma unroll
        for (int k = 1; k < 8; ++k) v[k] = cmul(v[k], tw2[k]);
        // ---- transpose 2 (pitch 65: conflict-free both sides) ----
        #pragma unroll
        for (int k = 0; k < 8; ++k)
            xch[k * 65 + lane] = make_float2(v[k].x, v[k].y);
        __builtin_amdgcn_s_waitcnt(0xc07f);
        __builtin_amdgcn_wave_barrier();
        {
            const int ra = (lane >> 3) * 65 + (lane & 7) * 8;
            #pragma unroll
            for (int r = 0; r < 8; ++r) {
                float2 tmp = xch[ra + r];
                v[r] = cpx{tmp.x, tmp.y};
            }
        }
        // ---- stage 3: DFT8 over n0 -> bin f = lane + 64*q1 in reg q1 ----
        dft8(v);
        // ---- Hermitian unpack + C = Y*conj(G) for bins f = lane + 64j ----
        cpx Cc[5];
        const int src = (64 - lane) & 63;
        #pragma unroll
        for (int jj = 0; jj < 5; ++jj) {
            cpx zk = v[jj];
            cpx zn;
            zn.x = __shfl(v[7 - jj].x, src);
            zn.y = __shfl(v[7 - jj].y, src);
            if (lane == 0) zn = v[(8 - jj) & 7];
            float ur = zk.x + zn.x, ui = zk.y - zn.y;   // 2*Y
            float vx = zk.x - zn.x, vy = zk.y + zn.y;   // 2i*G
            Cc[jj].x = fmaf(ur, vy, -ui * vx);
            Cc[jj].y = fmaf(ur, vx,  ui * vy);
        }
        if (accum) {
            #pragma unroll
            for (int jj = 0; jj < 4; ++jj) {
                cpx cc = Cc[jj];
                float aw = abs_angle(cc.x, cc.y);
                ip += aw;
                cpx cm;
                cm.x = __shfl_up(cc.x, 1);
                cm.y = __shfl_up(cc.y, 1);
                if (jj > 0) {
                    cpx cw;
                    cw.x = __shfl(Cc[jj - 1].x, 63);
                    cw.y = __shfl(Cc[jj - 1].y, 63);
                    if (lane == 0) cm = cw;
                }
                cpx qg = cmulc(cm, cc);
                gd += (jj == 0 && lane == 0) ? aw : abs_angle(qg.x, qg.y);
                if (hp) {
                    cpx qi = cmulc(Cp[jj], cc);
                    iaf += abs_angle(qi.x, qi.y);
                } else {
                    iaf += aw;
                }
            }
            {   // bin 256 (lane 0, reg 4)
                cpx cc = Cc[4];
                cpx cm;
                cm.x = __shfl(Cc[3].x, 63);
                cm.y = __shfl(Cc[3].y, 63);
                if (lane == 0) {
                    float aw = abs_angle(cc.x, cc.y);
                    ip += aw;
                    cpx qg = cmulc(cm, cc);
                    gd += abs_angle(qg.x, qg.y);
                    if (hp) {
                        cpx qi = cmulc(Cp[4], cc);
                        iaf += abs_angle(qi.x, qi.y);
                    } else {
                        iaf += aw;
                    }
                }
            }
        }
        #pragma unroll
        for (int jj = 0; jj < 5; ++jj) Cp[jj] = Cc[jj];
    };

    if (t0 < n_frames) {
        #pragma unroll 1
        for (int c = -1; c < FPW; ++c) {
            int t = t0 + c;
            if (c == -1) { if (!havep) continue; }
            else if (t >= n_frames) break;
            do_frame(t, c >= 0, havep || c > 0);
        }
    }

    // block reduce (idle waves contribute zeros)
    __syncthreads();
    for (int off = 32; off; off >>= 1) {
        ip  += __shfl_down(ip, off);
        gd  += __shfl_down(gd, off);
        iaf += __shfl_down(iaf, off);
    }
    if (lane == 0) { wsum[0][wid] = ip; wsum[1][wid] = gd; wsum[2][wid] = iaf; }
    __syncthreads();
    if (tid == 0) {
        const int slot = (int)(blockIdx.x & (NSLOTS - 1));
        atomicAdd(acc + 0 * NSLOTS + slot, wsum[0][0] + wsum[0][1] + wsum[0][2] + wsum[0][3]);
        atomicAdd(acc + 1 * NSLOTS + slot, wsum[1][0] + wsum[1][1] + wsum[1][2] + wsum[1][3]);
        atomicAdd(acc + 2 * NSLOTS + slot, wsum[2][0] + wsum[2][1] + wsum[2][2] + wsum[2][3]);
        __threadfence();
        is_last = (atomicAdd(ticket, 1) == (int)gridDim.x - 1);
    }
    __syncthreads();
    if (is_last) {
        for (int l = 0; l < 3; l++) {
            float vv = __hip_atomic_load(acc + l * NSLOTS + tid,
                                         __ATOMIC_RELAXED, __HIP_MEMORY_SCOPE_AGENT);
            for (int off = 32; off; off >>= 1) vv += __shfl_down(vv, off);
            if (lane == 0) wsum[l][wid] = vv;
        }
        __syncthreads();
        if (tid < 3)
            out[tid] = (wsum[tid][0] + wsum[tid][1] + wsum[tid][2] + wsum[tid][3]) * inv_count;
    }
}

extern "C" void kernel_launch(void* const* d_in, const int* in_sizes, int n_in,
                              void* d_out, int out_size, void* d_ws, size_t ws_size,
                              hipStream_t stream) {
    const float* y = (const float*)d_in[0];
    const float* g = (const float*)d_in[1];
    float* out = (float*)d_out;
    float* acc = (float*)d_ws;
    int* ticket = (int*)((char*)d_ws + 3 * NSLOTS * sizeof(float));
    const int T = in_sizes[0];
    const int n_frames = T / HOP + 1;                  // 32769
    const int n_chains = (n_frames + FPW - 1) / FPW;   // 4097
    const int n_blocks = (n_chains + 3) / 4;           // 1025

    hipMemsetAsync(d_ws, 0, 3 * NSLOTS * sizeof(float) + sizeof(int), stream);
    const float inv_count = 1.0f / (257.0f * (float)n_frames);
    phase_loss_kernel<<<n_blocks, 256, 0, stream>>>(y, g, acc, ticket, out,
                                                    T, n_frames, inv_count);
}

// Round 5
// 136.118 us; speedup vs baseline: 1.9257x; 1.0165x over previous
//
#include <hip/hip_runtime.h>
#include <math.h>

#define HOP     128
#define NSLOTS  256
#define FPW     8      // frames per wave (chain length)
#define PI_F    3.14159265358979323846f
#define PI2_F   1.57079632679489661923f
#define K8      0.70710678118654752440f

// Zero-instruction ordering fence for intra-wave LDS cross-lane handoffs:
// the "memory" clobber stops LLVM hoisting the (per-lane provably disjoint)
// reads above the writes; the DS pipe is in-order per wave, so no s_waitcnt
// drain is needed for data correctness.
#define LDS_FENCE() do { __asm__ volatile("" ::: "memory"); \
                         __builtin_amdgcn_wave_barrier(); } while (0)

struct cpx { float x, y; };
__device__ __forceinline__ cpx cadd(cpx a, cpx b){ return {a.x+b.x, a.y+b.y}; }
__device__ __forceinline__ cpx csub(cpx a, cpx b){ return {a.x-b.x, a.y-b.y}; }
__device__ __forceinline__ cpx cmul(cpx a, cpx b){
    return {fmaf(a.x,b.x,-a.y*b.y), fmaf(a.x,b.y, a.y*b.x)};
}
__device__ __forceinline__ cpx cmulc(cpx a, cpx b){  // a*conj(b)
    return {fmaf(a.x,b.x, a.y*b.y), fmaf(a.y,b.x,-a.x*b.y)};
}

// |atan2(im,re)| in [0,pi] — same poly that passed rounds 2-3.
__device__ __forceinline__ float abs_angle(float re, float im) {
    float a = fabsf(im), b = fabsf(re);
    float mn = fminf(a, b), mx = fmaxf(a, b);
    float t = __fdividef(mn, fmaxf(mx, 1e-37f));
    float t2 = t * t;
    float p = fmaf(t2, -0.0117212f, 0.05265332f);
    p = fmaf(t2, p, -0.11643287f);
    p = fmaf(t2, p, 0.19354346f);
    p = fmaf(t2, p, -0.33262347f);
    p = fmaf(t2, p, 0.99997726f);
    float r = t * p;
    r = (a > b) ? (PI2_F - r) : r;
    r = (re < 0.f) ? (PI_F - r) : r;
    return r;
}

// In-register 8-point DFT, natural-order output. X[k] = sum_n v[n] W8^{nk}.
__device__ __forceinline__ void dft8(cpx v[8]) {
    cpx a0=cadd(v[0],v[4]), a1=cadd(v[1],v[5]), a2=cadd(v[2],v[6]), a3=cadd(v[3],v[7]);
    cpx b0=csub(v[0],v[4]), b1=csub(v[1],v[5]), b2=csub(v[2],v[6]), b3=csub(v[3],v[7]);
    b1 = cpx{K8*(b1.x+b1.y), K8*(b1.y-b1.x)};   // * e^{-i pi/4}
    b2 = cpx{b2.y, -b2.x};                      // * -i
    b3 = cpx{K8*(b3.y-b3.x), -K8*(b3.x+b3.y)};  // * e^{-3i pi/4}
    cpx c0=cadd(a0,a2), c2=csub(a0,a2);
    cpx c1=cadd(a1,a3), c3=csub(a1,a3); c3 = cpx{c3.y, -c3.x};
    cpx d0=cadd(b0,b2), d2=csub(b0,b2);
    cpx d1=cadd(b1,b3), d3=csub(b1,b3); d3 = cpx{d3.y, -d3.x};
    v[0]=cadd(c0,c1); v[4]=csub(c0,c1);
    v[2]=cadd(c2,c3); v[6]=csub(c2,c3);
    v[1]=cadd(d0,d1); v[5]=csub(d0,d1);
    v[3]=cadd(d2,d3); v[7]=csub(d2,d3);
}

__global__ __launch_bounds__(256, 4) void phase_loss_kernel(
        const float* __restrict__ y, const float* __restrict__ g,
        float* __restrict__ acc, int* __restrict__ ticket,
        float* __restrict__ out, int T, int n_frames, float inv_count) {
    __shared__ float2 xch_all[4][576];   // per-wave transpose scratch (aliased as Z)
    __shared__ float2 cl_all[4][258];    // per-wave C array (+1 garbage slot at [0])
    __shared__ float wsum[3][4];
    __shared__ int is_last;

    const int tid  = threadIdx.x;
    const int lane = tid & 63;
    const int wid  = tid >> 6;
    float2* xch = xch_all[wid];
    float2* Cl  = cl_all[wid] + 1;       // Cl[-1] is a valid (garbage) slot

    // Per-lane twiddles in registers, once per kernel.
    cpx tw1[8], tw2[8];
    #pragma unroll
    for (int k = 0; k < 8; ++k) {
        float a1 = -(2.0f * PI_F / 512.0f) * (float)(lane * k);
        __sincosf(a1, &tw1[k].y, &tw1[k].x);
        float a2 = -(2.0f * PI_F / 64.0f) * (float)((lane & 7) * k);
        __sincosf(a2, &tw2[k].y, &tw2[k].x);
    }

    float ip = 0.f, gd = 0.f, iaf = 0.f;
    cpx Cp[5];
    const int tmax_int = (T - 256) / HOP;   // frames [2, tmax_int] need no reflect

    auto do_frame = [&](int t, bool accum, bool hp) {
        cpx v[8];
        const int base = t * HOP - 256 + lane;
        if (t >= 2 && t <= tmax_int) {       // fast path: no reflect clamps
            #pragma unroll
            for (int r = 0; r < 8; ++r) {
                int j = base + r * 64;
                v[r].x = y[j]; v[r].y = g[j];
            }
        } else {
            #pragma unroll
            for (int r = 0; r < 8; ++r) {
                int j = base + r * 64;
                j = (j < 0) ? -j : j;
                j = (j >= T) ? (2 * T - 2 - j) : j;
                v[r].x = y[j]; v[r].y = g[j];
            }
        }
        // stage 1: DFT8 over n2, twiddle W512^{lane*k}
        dft8(v);
        #pragma unroll
        for (int k = 1; k < 8; ++k) v[k] = cmul(v[k], tw1[k]);
        LDS_FENCE();   // orders prev frame's Z/Cl reads vs these writes
        #pragma unroll
        for (int k = 0; k < 8; ++k)
            xch[k * 72 + lane] = make_float2(v[k].x, v[k].y);
        LDS_FENCE();
        {
            const int ra = (lane >> 3) * 72 + (lane & 7);
            #pragma unroll
            for (int r = 0; r < 8; ++r) {
                float2 tmp = xch[ra + r * 8];
                v[r] = cpx{tmp.x, tmp.y};
            }
        }
        // stage 2: DFT8, twiddle W64^{(lane&7)*k}
        dft8(v);
        #pragma unroll
        for (int k = 1; k < 8; ++k) v[k] = cmul(v[k], tw2[k]);
        LDS_FENCE();
        #pragma unroll
        for (int k = 0; k < 8; ++k)
            xch[k * 65 + lane] = make_float2(v[k].x, v[k].y);
        LDS_FENCE();
        {
            const int ra = (lane >> 3) * 65 + (lane & 7) * 8;
            #pragma unroll
            for (int r = 0; r < 8; ++r) {
                float2 tmp = xch[ra + r];
                v[r] = cpx{tmp.x, tmp.y};
            }
        }
        // stage 3: DFT8 -> bin f = lane + 64*reg, full spectrum in regs
        dft8(v);
        // write Z over the (dead) xch buffer; Hermitian partner = Z[(512-f)&511]
        float2* Z = xch;
        LDS_FENCE();
        #pragma unroll
        for (int j = 0; j < 8; ++j)
            Z[lane + (j << 6)] = make_float2(v[j].x, v[j].y);
        LDS_FENCE();
        cpx Cc[5];
        #pragma unroll
        for (int jj = 0; jj < 5; ++jj) {
            const int f = lane + (jj << 6);
            float2 tmp = Z[(512 - f) & 511];
            float ur = v[jj].x + tmp.x, ui = v[jj].y - tmp.y;   // 2*Y
            float vx = v[jj].x - tmp.x, vy = v[jj].y + tmp.y;   // 2i*G
            Cc[jj].x = fmaf(ur, vy, -ui * vx);                  // C = Y*conj(G), x4
            Cc[jj].y = fmaf(ur, vx,  ui * vy);
        }
        if (accum) {
            LDS_FENCE();
            #pragma unroll
            for (int jj = 0; jj < 4; ++jj)
                Cl[lane + (jj << 6)] = make_float2(Cc[jj].x, Cc[jj].y);
            if (lane == 0) Cl[256] = make_float2(Cc[4].x, Cc[4].y);
            LDS_FENCE();   // cross-lane handoff: Cl[x-1] reads need lane x-1's write
            cpx cm[4];
            #pragma unroll
            for (int jj = 0; jj < 4; ++jj) {
                float2 tmp = Cl[lane + (jj << 6) - 1];   // Cl[-1] garbage, discarded
                cm[jj] = cpx{tmp.x, tmp.y};
            }
            float2 c255 = Cl[255];
            #pragma unroll
            for (int jj = 0; jj < 4; ++jj) {
                cpx cc = Cc[jj];
                float aw = abs_angle(cc.x, cc.y);
                ip += aw;
                cpx qg = cmulc(cm[jj], cc);
                float gt = abs_angle(qg.x, qg.y);
                gd += (jj == 0 && lane == 0) ? aw : gt;   // gd row 0 term == ip term
                if (hp) {
                    cpx qi = cmulc(Cp[jj], cc);
                    iaf += abs_angle(qi.x, qi.y);
                } else {
                    iaf += aw;                             // iaf col 0 term == ip term
                }
            }
            if (lane == 0) {   // bin 256
                cpx cc = Cc[4];
                float aw = abs_angle(cc.x, cc.y);
                ip += aw;
                cpx qg = cmulc(cpx{c255.x, c255.y}, cc);
                gd += abs_angle(qg.x, qg.y);
                if (hp) {
                    cpx qi = cmulc(Cp[4], cc);
                    iaf += abs_angle(qi.x, qi.y);
                } else {
                    iaf += aw;
                }
            }
        }
        #pragma unroll
        for (int jj = 0; jj < 5; ++jj) Cp[jj] = Cc[jj];
    };

    const int chain   = (blockIdx.x << 2) | wid;        // 0 .. 4*gridDim.x-1
    const int nchains = (int)(gridDim.x << 2);
    const int t0 = chain * FPW;
    int tend = t0 + FPW;
    if (chain == nchains - 1) tend = n_frames;          // last chain takes remainder
    const bool havep = (t0 > 0);

    if (havep) do_frame(t0 - 1, false, false);
    #pragma unroll 2
    for (int t = t0; t < tend; ++t)
        do_frame(t, true, havep || (t > t0));

    // block reduce
    __syncthreads();
    for (int off = 32; off; off >>= 1) {
        ip  += __shfl_down(ip, off);
        gd  += __shfl_down(gd, off);
        iaf += __shfl_down(iaf, off);
    }
    if (lane == 0) { wsum[0][wid] = ip; wsum[1][wid] = gd; wsum[2][wid] = iaf; }
    __syncthreads();
    if (tid == 0) {
        const int slot = (int)(blockIdx.x & (NSLOTS - 1));
        atomicAdd(acc + 0 * NSLOTS + slot, wsum[0][0] + wsum[0][1] + wsum[0][2] + wsum[0][3]);
        atomicAdd(acc + 1 * NSLOTS + slot, wsum[1][0] + wsum[1][1] + wsum[1][2] + wsum[1][3]);
        atomicAdd(acc + 2 * NSLOTS + slot, wsum[2][0] + wsum[2][1] + wsum[2][2] + wsum[2][3]);
        __threadfence();
        is_last = (atomicAdd(ticket, 1) == (int)gridDim.x - 1);
    }
    __syncthreads();
    if (is_last) {
        for (int l = 0; l < 3; l++) {
            float vv = __hip_atomic_load(acc + l * NSLOTS + tid,
                                         __ATOMIC_RELAXED, __HIP_MEMORY_SCOPE_AGENT);
            for (int off = 32; off; off >>= 1) vv += __shfl_down(vv, off);
            if (lane == 0) wsum[l][wid] = vv;
        }
        __syncthreads();
        if (tid < 3)
            out[tid] = (wsum[tid][0] + wsum[tid][1] + wsum[tid][2] + wsum[tid][3]) * inv_count;
    }
}

extern "C" void kernel_launch(void* const* d_in, const int* in_sizes, int n_in,
                              void* d_out, int out_size, void* d_ws, size_t ws_size,
                              hipStream_t stream) {
    const float* y = (const float*)d_in[0];
    const float* g = (const float*)d_in[1];
    float* out = (float*)d_out;
    float* acc = (float*)d_ws;
    int* ticket = (int*)((char*)d_ws + 3 * NSLOTS * sizeof(float));
    const int T = in_sizes[0];
    const int n_frames = T / HOP + 1;                  // 32769
    int n_blocks = n_frames / (FPW * 4);               // 1024 (last chain absorbs rest)
    if (n_blocks < 1) n_blocks = 1;

    hipMemsetAsync(d_ws, 0, 3 * NSLOTS * sizeof(float) + sizeof(int), stream);
    const float inv_count = 1.0f / (257.0f * (float)n_frames);
    phase_loss_kernel<<<n_blocks, 256, 0, stream>>>(y, g, acc, ticket, out,
                                                    T, n_frames, inv_count);
}